// Round 10
// baseline (772.967 us; speedup 1.0000x reference)
//
#include <hip/hip_runtime.h>
#include <stdint.h>

// B=4, DIM=192, H=W=64, N=4096, HEADS=8, HD=24, SR=4, PLEN=256, LL=9
// All inputs f32, output f32.

__device__ __forceinline__ float b2f(unsigned short u) {
  return __uint_as_float(((unsigned)u) << 16);
}
__device__ __forceinline__ unsigned short f2b(float f) {
  unsigned x = __float_as_uint(f);
  return (unsigned short)((x + 0x7fffu + ((x >> 16) & 1u)) >> 16);
}

// ---------------- workspace layout (floats) ----------------
constexpr size_t OFF_T    = 0;          // (B,N,192)
constexpr size_t OFF_KMAP = 3145728;    // (B,384,N)
constexpr size_t OFF_QN   = 9437184;    // (B,8,24,N); reused as pout (B,192,N) after attn
constexpr size_t OFF_QS   = 12582912;   // (B,8,24,N)
constexpr size_t OFF_CTX  = 15728640;   // (B,8,24,N)  (early: scratch for W transposes)
constexpr size_t OFF_POOL = 18874368;   // (B,256,192)
constexpr size_t OFF_KP   = 19070976;   // (B,8,256,24)
constexpr size_t OFF_VP   = 19267584;   // (B,8,256,24)
constexpr size_t OFF_CPB  = 19464192;   // (T,8)
constexpr size_t OFF_BIAS = 19595264;   // bf16 (8,256,4096) = 16.7 M ushort
constexpr size_t OFF_WTC  = OFF_CTX;              // conv wt [1728][192]
constexpr size_t OFF_QT   = OFF_CTX + 331776;     // [192][192]
constexpr size_t OFF_KVT  = OFF_CTX + 368640;     // [192][384]
constexpr size_t OFF_SRT  = OFF_CTX + 442368;     // [192][192]
constexpr size_t OFF_PJT  = OFF_KMAP;             // [192][192], created AFTER attn

// ---------------- weight transposes ----------------
__global__ __launch_bounds__(256) void k_wt_conv(const float* __restrict__ pw,
                                                 float* __restrict__ wt) {
  int i = blockIdx.x * 256 + threadIdx.x;
  if (i >= 331776) return;
  int oc = i % 192, k = i / 192;
  wt[i] = pw[(size_t)oc * 1728 + k];
}
__global__ __launch_bounds__(256) void k_wt_gen(const float* __restrict__ src,
                                                float* __restrict__ dst, int O, int K) {
  int i = blockIdx.x * 256 + threadIdx.x;
  if (i >= O * K) return;
  int o = i % O, k = i / O;
  dst[i] = src[(size_t)o * K + k];
}

// ---------------- 3x3 conv; 2 rows/lane, 12 oc/wave, reg-prefetch pipeline ----------------
__global__ __launch_bounds__(256) void k_conv(
    const float* __restrict__ x, const float* __restrict__ wtc,
    const float* __restrict__ bf, float* __restrict__ t) {
  __shared__ __align__(16) float wl[72 * 48];
  __shared__ float xl[8 * 4 * 66];
  const int tid = threadIdx.x;
  const int lane = tid & 63;
  const int wv = __builtin_amdgcn_readfirstlane(tid >> 6);
  const int h0 = blockIdx.x * 2;
  const int b = blockIdx.y;
  const int obase = blockIdx.z * 48;
  const int ow = obase + wv * 12;

  float acc0[12], acc1[12];
#pragma unroll
  for (int j = 0; j < 12; ++j) { acc0[j] = 0.f; acc1[j] = 0.f; }

  float xr[9];
  float4 wr[4];
  auto loadx = [&](int ic0) {
#pragma unroll
    for (int s = 0; s < 9; ++s) {
      int f = tid + s * 256;
      float v = 0.f;
      if (f < 2112) {
        int ii = f / 264;
        int rem = f - ii * 264;
        int r = rem / 66;
        int wp = rem - r * 66;
        int hh = h0 + r - 1, ww = wp - 1;
        if (hh >= 0 && hh < 64 && ww >= 0 && ww < 64)
          v = x[((size_t)(b * 192 + ic0 * 8 + ii) << 12) + (hh << 6) + ww];
      }
      xr[s] = v;
    }
  };
  auto loadw = [&](int ic0) {
#pragma unroll
    for (int s = 0; s < 4; ++s) {
      int f4 = tid + s * 256;
      if (f4 < 864) {
        int kk = f4 / 12, j = f4 - kk * 12;
        wr[s] = ((const float4*)(wtc + (size_t)(ic0 * 72 + kk) * 192 + obase))[j];
      }
    }
  };
  loadx(0); loadw(0);

  for (int ic0 = 0; ic0 < 24; ++ic0) {
    __syncthreads();
#pragma unroll
    for (int s = 0; s < 9; ++s) {
      int f = tid + s * 256;
      if (f < 2112) {
        int ii = f / 264;
        int rem = f - ii * 264;
        int r = rem / 66;
        int wp = rem - r * 66;
        xl[(ii * 4 + r) * 66 + wp] = xr[s];
      }
    }
#pragma unroll
    for (int s = 0; s < 4; ++s) {
      int f4 = tid + s * 256;
      if (f4 < 864) ((float4*)wl)[f4] = wr[s];
    }
    __syncthreads();
    if (ic0 < 23) { loadx(ic0 + 1); loadw(ic0 + 1); }
#pragma unroll 1
    for (int ii = 0; ii < 8; ++ii) {
#pragma unroll
      for (int r = 0; r < 3; ++r) {
        const float* xr0 = &xl[(ii * 4 + r) * 66 + lane];
        const float* xr1 = xr0 + 66;
        float a0 = xr0[0], a1 = xr0[1], a2 = xr0[2];
        float c0 = xr1[0], c1 = xr1[1], c2 = xr1[2];
#pragma unroll
        for (int kw = 0; kw < 3; ++kw) {
          float xv0 = (kw == 0) ? a0 : ((kw == 1) ? a1 : a2);
          float xv1 = (kw == 0) ? c0 : ((kw == 1) ? c1 : c2);
          const float4* wrow = (const float4*)&wl[(ii * 9 + r * 3 + kw) * 48 + wv * 12];
#pragma unroll
          for (int j4 = 0; j4 < 3; ++j4) {
            float4 w4 = wrow[j4];
            acc0[j4 * 4 + 0] += xv0 * w4.x;  acc1[j4 * 4 + 0] += xv1 * w4.x;
            acc0[j4 * 4 + 1] += xv0 * w4.y;  acc1[j4 * 4 + 1] += xv1 * w4.y;
            acc0[j4 * 4 + 2] += xv0 * w4.z;  acc1[j4 * 4 + 2] += xv1 * w4.z;
            acc0[j4 * 4 + 3] += xv0 * w4.w;  acc1[j4 * 4 + 3] += xv1 * w4.w;
          }
        }
      }
    }
  }
  float* out0 = t + ((size_t)b * 4096 + h0 * 64 + lane) * 192 + ow;
  float* out1 = out0 + 64 * 192;
#pragma unroll
  for (int j4 = 0; j4 < 3; ++j4) {
    float4 bb4 = *(const float4*)&bf[ow + j4 * 4];
    float4 v0, v1;
    v0.x = acc0[j4 * 4 + 0] + bb4.x;  v1.x = acc1[j4 * 4 + 0] + bb4.x;
    v0.y = acc0[j4 * 4 + 1] + bb4.y;  v1.y = acc1[j4 * 4 + 1] + bb4.y;
    v0.z = acc0[j4 * 4 + 2] + bb4.z;  v1.z = acc1[j4 * 4 + 2] + bb4.z;
    v0.w = acc0[j4 * 4 + 3] + bb4.w;  v1.w = acc1[j4 * 4 + 3] + bb4.w;
    ((float4*)out0)[j4] = v0;
    ((float4*)out1)[j4] = v1;
  }
}

// ---------------- LN over 192 channels, in-place (wave per row) ----------------
__global__ __launch_bounds__(256) void k_ln_rows(float* __restrict__ data,
    const float* __restrict__ g, const float* __restrict__ be, int rows) {
  int lane = threadIdx.x & 63;
  int wv = threadIdx.x >> 6;
  int row = blockIdx.x * 4 + wv;
  if (row >= rows) return;
  float* p = data + (size_t)row * 192;
  float v0 = p[lane], v1 = p[lane + 64], v2 = p[lane + 128];
  float s = v0 + v1 + v2;
  float sq = v0 * v0 + v1 * v1 + v2 * v2;
#pragma unroll
  for (int m = 32; m >= 1; m >>= 1) {
    s += __shfl_xor(s, m, 64);
    sq += __shfl_xor(sq, m, 64);
  }
  float mean = s * (1.f / 192.f);
  float var = sq * (1.f / 192.f) - mean * mean;
  float rstd = rsqrtf(var + 1e-5f);
  p[lane]       = (v0 - mean) * rstd * g[lane]       + be[lane];
  p[lane + 64]  = (v1 - mean) * rstd * g[lane + 64]  + be[lane + 64];
  p[lane + 128] = (v2 - mean) * rstd * g[lane + 128] + be[lane + 128];
}

// ======== GEMM tile core w/ register-prefetch dbuf ========
template <int OCB, typename GXV, typename GXD>
__device__ __forceinline__ void gemm_tiles(
    float* __restrict__ wl, float* __restrict__ xs, int tid, int lane, int wv,
    const float* __restrict__ wt, int ostr, int obase,
    float (&acc)[OCB / 4], GXV gxv, GXD gxd) {
  constexpr int NPF4 = OCB / 4;
  constexpr int NW4 = OCB / 16;
  constexpr int NWR = (32 * NPF4 + 255) / 256;
  constexpr bool WEXACT = (32 * NPF4 % 256) == 0;
  float xr[8];
  float4 wr[NWR];
  auto loadx = [&](int k0) {
#pragma unroll
    for (int s = 0; s < 8; ++s) xr[s] = gxv(k0, tid + s * 256);
  };
  auto loadw = [&](int k0) {
#pragma unroll
    for (int s = 0; s < NWR; ++s) {
      int f4 = tid + s * 256;
      if (WEXACT || f4 < 32 * NPF4) {
        int kk = f4 / NPF4, j = f4 - kk * NPF4;
        wr[s] = ((const float4*)(wt + (size_t)(k0 + kk) * ostr + obase))[j];
      }
    }
  };
  loadx(0); loadw(0);
  for (int kt = 0; kt < 6; ++kt) {
    __syncthreads();
#pragma unroll
    for (int s = 0; s < 8; ++s) xs[gxd(tid + s * 256)] = xr[s];
#pragma unroll
    for (int s = 0; s < NWR; ++s) {
      int f4 = tid + s * 256;
      if (WEXACT || f4 < 32 * NPF4) ((float4*)wl)[f4] = wr[s];
    }
    __syncthreads();
    if (kt < 5) { loadx((kt + 1) * 32); loadw((kt + 1) * 32); }
#pragma unroll 4
    for (int kk = 0; kk < 32; ++kk) {
      float xv = xs[kk * 66 + lane];
      const float4* wrow = (const float4*)&wl[kk * OCB + wv * NW4 * 4];
#pragma unroll
      for (int j4 = 0; j4 < NW4; ++j4) {
        float4 w4 = wrow[j4];
        acc[j4 * 4 + 0] += xv * w4.x;
        acc[j4 * 4 + 1] += xv * w4.y;
        acc[j4 * 4 + 2] += xv * w4.z;
        acc[j4 * 4 + 3] += xv * w4.w;
      }
    }
  }
}

// ---------------- q GEMM (96 oc = 4 heads/block) -> l2norm -> scaled ----------------
__global__ __launch_bounds__(256) void k_q(
    const float* __restrict__ t, const float* __restrict__ qt, const float* __restrict__ qb,
    const float* __restrict__ qe, const float* __restrict__ tmp, const float* __restrict__ ss,
    float* __restrict__ qno, float* __restrict__ qso) {
  __shared__ __align__(16) float wl[32 * 96];
  __shared__ float xs[32 * 66];
  const int tid = threadIdx.x;
  const int lane = tid & 63;
  const int wv = __builtin_amdgcn_readfirstlane(tid >> 6);
  const int n0 = blockIdx.x * 64;
  const int b = blockIdx.y;
  const int obase = blockIdx.z * 96;
  const int hh = blockIdx.z * 4 + wv;
  const int oc0 = obase + wv * 24;
  float acc[24];
#pragma unroll
  for (int j = 0; j < 24; ++j) acc[j] = 0.f;

  gemm_tiles<96>(wl, xs, tid, lane, wv, qt, 192, obase, acc,
    [&](int k0, int f) {
      int nl = f >> 5, kk = f & 31;
      return t[((size_t)b * 4096 + n0 + nl) * 192 + k0 + kk];
    },
    [&](int f) { return (f & 31) * 66 + (f >> 5); });

  const int n = n0 + lane;
  float ssv = ss[n];
  float sumsq = 0.f;
#pragma unroll
  for (int d = 0; d < 24; ++d) {
    float v = acc[d] + qb[oc0 + d];
    sumsq += v * v;
  }
  float rn = 1.f / fmaxf(sqrtf(sumsq), 1e-12f);
  float sp = log1pf(__expf(tmp[hh]));
#pragma unroll
  for (int d = 0; d < 24; ++d) {
    float qv = (acc[d] + qb[oc0 + d]) * rn;
    size_t o = ((size_t)(b * 8 + hh) * 24 + d) * 4096 + n;
    qno[o] = qv;
    qso[o] = (qv + qe[hh * 24 + d]) * sp * ssv;
  }
}

// ---------------- kv GEMM (96 of 384 oc/block) -> kmap[b][c][n] ----------------
__global__ __launch_bounds__(256) void k_kv(
    const float* __restrict__ t, const float* __restrict__ kvt, const float* __restrict__ kb_,
    float* __restrict__ kmap) {
  __shared__ __align__(16) float wl[32 * 96];
  __shared__ float xs[32 * 66];
  const int tid = threadIdx.x;
  const int lane = tid & 63;
  const int wv = __builtin_amdgcn_readfirstlane(tid >> 6);
  const int n0 = blockIdx.x * 64;
  const int b = blockIdx.y;
  const int obase = blockIdx.z * 96;
  const int oc0 = obase + wv * 24;
  const int n = n0 + lane;
  float acc[24];
#pragma unroll
  for (int j = 0; j < 24; ++j) acc[j] = 0.f;

  gemm_tiles<96>(wl, xs, tid, lane, wv, kvt, 384, obase, acc,
    [&](int k0, int f) {
      int nl = f >> 5, kk = f & 31;
      return t[((size_t)b * 4096 + n0 + nl) * 192 + k0 + kk];
    },
    [&](int f) { return (f & 31) * 66 + (f >> 5); });

  if (oc0 < 192) {
    float sumsq = 0.f;
#pragma unroll
    for (int d = 0; d < 24; ++d) {
      float v = acc[d] + kb_[oc0 + d];
      sumsq += v * v;
    }
    float rn = 1.f / fmaxf(sqrtf(sumsq), 1e-12f);
#pragma unroll
    for (int d = 0; d < 24; ++d)
      kmap[((size_t)b * 384 + oc0 + d) * 4096 + n] = (acc[d] + kb_[oc0 + d]) * rn;
  } else {
#pragma unroll
    for (int d = 0; d < 24; ++d)
      kmap[((size_t)b * 384 + oc0 + d) * 4096 + n] = acc[d] + kb_[oc0 + d];
  }
}

// ---------------- sr GEMM (48 oc/block) + exact gelu + 4x4 mean-pool ----------------
__device__ __forceinline__ float gelu_exact(float v) {
  float u = v * 0.70710678118654752f;
  float a = fabsf(u);
  float tt = 1.f / (1.f + 0.3275911f * a);
  float poly = ((((1.061405429f * tt - 1.453152027f) * tt + 1.421413741f) * tt
                 - 0.284496736f) * tt + 0.254829592f) * tt;
  float erfa = 1.f - poly * __expf(-a * a);
  float erfv = (u < 0.f) ? -erfa : erfa;
  return 0.5f * v * (1.f + erfv);
}

__global__ __launch_bounds__(256) void k_srpool(
    const float* __restrict__ t, const float* __restrict__ srt, const float* __restrict__ sb,
    float* __restrict__ pooled) {
  __shared__ __align__(16) float wl[32 * 48];
  __shared__ float xs[32 * 66];
  const int tid = threadIdx.x;
  const int lane = tid & 63;
  const int wv = __builtin_amdgcn_readfirstlane(tid >> 6);
  const int wx = blockIdx.x & 3;
  const int obase = (blockIdx.x >> 2) * 48;
  const int ph = blockIdx.y;
  const int b = blockIdx.z;
  const int oc0 = obase + wv * 12;
  float acc[12];
#pragma unroll
  for (int j = 0; j < 12; ++j) acc[j] = 0.f;

  gemm_tiles<48>(wl, xs, tid, lane, wv, srt, 192, obase, acc,
    [&](int k0, int f) {
      int pl = f >> 5, kk = f & 31;
      int row = (ph * 4 + (pl >> 4)) * 64 + wx * 16 + (pl & 15);
      return t[((size_t)b * 4096 + row) * 192 + k0 + kk];
    },
    [&](int f) { return (f & 31) * 66 + (f >> 5); });

#pragma unroll
  for (int j = 0; j < 12; ++j) {
    float gv = gelu_exact(acc[j] + sb[oc0 + j]);
    gv += __shfl_xor(gv, 1, 64);
    gv += __shfl_xor(gv, 2, 64);
    gv += __shfl_xor(gv, 16, 64);
    gv += __shfl_xor(gv, 32, 64);
    if ((lane & 51) == 0) {
      int cell = (lane >> 2) & 3;
      int p = ph * 16 + wx * 4 + cell;
      pooled[((size_t)b * 256 + p) * 192 + oc0 + j] = gv * (1.f / 16.f);
    }
  }
}

// ---------------- pooled kv (96 of 384 oc/block) -> kp/vp [b][h][m][24] ----------------
__global__ __launch_bounds__(256) void k_kvp(
    const float* __restrict__ pooled, const float* __restrict__ kvt, const float* __restrict__ kb_,
    float* __restrict__ kp, float* __restrict__ vp) {
  __shared__ __align__(16) float wl[32 * 96];
  __shared__ float xs[32 * 66];
  const int tid = threadIdx.x;
  const int lane = tid & 63;
  const int wv = __builtin_amdgcn_readfirstlane(tid >> 6);
  const int r0 = blockIdx.x * 64;
  const int obase = blockIdx.y * 96;
  const int oc0 = obase + wv * 24;
  const int row = r0 + lane;
  const int b = row >> 8;
  const int m = row & 255;
  float acc[24];
#pragma unroll
  for (int j = 0; j < 24; ++j) acc[j] = 0.f;

  gemm_tiles<96>(wl, xs, tid, lane, wv, kvt, 384, obase, acc,
    [&](int k0, int f) {
      int nl = f >> 5, kk = f & 31;
      return pooled[(size_t)(r0 + nl) * 192 + k0 + kk];
    },
    [&](int f) { return (f & 31) * 66 + (f >> 5); });

  if (oc0 < 192) {
    int hh = oc0 / 24;
    float sumsq = 0.f;
#pragma unroll
    for (int d = 0; d < 24; ++d) {
      float v = acc[d] + kb_[oc0 + d];
      sumsq += v * v;
    }
    float rn = 1.f / fmaxf(sqrtf(sumsq), 1e-12f);
#pragma unroll
    for (int d = 0; d < 24; ++d)
      kp[(((size_t)(b * 8 + hh)) * 256 + m) * 24 + d] = (acc[d] + kb_[oc0 + d]) * rn;
  } else {
    int hh = (oc0 - 192) / 24;
#pragma unroll
    for (int d = 0; d < 24; ++d)
      vp[(((size_t)(b * 8 + hh)) * 256 + m) * 24 + d] = acc[d] + kb_[oc0 + d];
  }
}

// ---------------- cpb MLP: (T,2) -> (T,8), weights staged in LDS ----------------
__global__ __launch_bounds__(256) void k_cpb(
    const float* __restrict__ coords, const float* __restrict__ c1w,
    const float* __restrict__ c1b, const float* __restrict__ c2w,
    const float* __restrict__ c2b, float* __restrict__ cpb, int T) {
  __shared__ float s1w[1024];
  __shared__ float s1b[512];
  __shared__ __align__(16) float s2w[512 * 8];
  const int tid = threadIdx.x;
  for (int f = tid; f < 1024; f += 256) s1w[f] = c1w[f];
  for (int f = tid; f < 512; f += 256) s1b[f] = c1b[f];
  for (int f = tid; f < 4096; f += 256) {
    int h = f >> 9, j = f & 511;
    s2w[j * 8 + h] = c2w[f];
  }
  __syncthreads();
  int i = blockIdx.x * 256 + tid;
  int ic = (i < T) ? i : (T - 1);
  float x0 = coords[2 * ic], y0 = coords[2 * ic + 1];
  float a[8];
#pragma unroll
  for (int h = 0; h < 8; ++h) a[h] = c2b[h];
#pragma unroll 4
  for (int j = 0; j < 512; ++j) {
    float hv = fmaxf(s1w[2 * j] * x0 + s1w[2 * j + 1] * y0 + s1b[j], 0.f);
    const float4* w2 = (const float4*)&s2w[j * 8];
    float4 wA = w2[0], wB = w2[1];
    a[0] += hv * wA.x; a[1] += hv * wA.y; a[2] += hv * wA.z; a[3] += hv * wA.w;
    a[4] += hv * wB.x; a[5] += hv * wB.y; a[6] += hv * wB.z; a[7] += hv * wB.w;
  }
  if (i < T) {
#pragma unroll
    for (int h = 0; h < 8; ++h) cpb[(size_t)i * 8 + h] = a[h];
  }
}

// ---------------- pool bias gather: bt[h][m][n] (bf16) ----------------
__global__ __launch_bounds__(256) void k_bias(
    const int* __restrict__ rel, const float* __restrict__ cpb,
    unsigned short* __restrict__ bt) {
  int n = blockIdx.x * 256 + threadIdx.x;
  int m = blockIdx.y;
  int idx = rel[(size_t)n * 256 + m];
  const float4* c4 = (const float4*)(cpb + (size_t)idx * 8);
  float4 A = c4[0], Bv = c4[1];
  float vals[8] = {A.x, A.y, A.z, A.w, Bv.x, Bv.y, Bv.z, Bv.w};
#pragma unroll
  for (int h = 0; h < 8; ++h)
    bt[((size_t)(h * 256 + m)) * 4096 + n] = f2b(vals[h]);
}

// ---------------- fused attention; pool m-loop split across waves ----------------
// Phase 1: wave w owns pixel row w of the block -> local 9-tap part (ctxA regs, ctxB+S -> LDS).
// Phase 2: wave w handles m in [64w,64w+64) for ALL 4 rows (4n/lane) -> partial ctxP,S.
// Phase 3: partials accumulated into cls; wave w finalizes its own row (ctxA still in regs).
__global__ __launch_bounds__(256) void k_attn(
    const float* __restrict__ qs_g, const float* __restrict__ qn_g,
    const float* __restrict__ kmap, const float* __restrict__ kp, const float* __restrict__ vp,
    const unsigned short* __restrict__ bt, const float* __restrict__ rpb,
    const float* __restrict__ lt, const float* __restrict__ lb,
    float* __restrict__ ctx) {
  __shared__ __align__(16) float kl[256 * 24];   // 24 KB
  __shared__ __align__(16) float vl[256 * 24];   // 24 KB
  __shared__ float cls[4][64][26];               // 26.6 KB  [row][col][ctxB 24 | S | pad]
  const int tid = threadIdx.x;
  const int lane = tid & 63;
  const int wv = __builtin_amdgcn_readfirstlane(tid >> 6);
  const int h = blockIdx.y;
  const int b = blockIdx.z;
  const int nblk = blockIdx.x * 256;
  const int n = nblk + wv * 64 + lane;
  const int hpix = __builtin_amdgcn_readfirstlane(n >> 6);
  const int wpix = n & 63;
  const float SHIFT = 15.f;

  // stage kp/vp (whole (b,h): 256 x 24 each)
  {
    const float4* kps = (const float4*)(kp + (size_t)(b * 8 + h) * 6144);
    const float4* vps = (const float4*)(vp + (size_t)(b * 8 + h) * 6144);
    float4* kld = (float4*)kl;
    float4* vld = (float4*)vl;
    for (int f = tid; f < 1536; f += 256) {
      kld[f] = kps[f];
      vld[f] = vps[f];
    }
  }

  // ---- phase 1: local 9-neighbor part for own row ----
  float qsv[24], ctxA[24];
  {
    float qnv[24], ctxB[24];
    const float* qsb = qs_g + ((size_t)(b * 8 + h) * 24) * 4096 + n;
    const float* qnb = qn_g + ((size_t)(b * 8 + h) * 24) * 4096 + n;
#pragma unroll
    for (int d = 0; d < 24; ++d) {
      qsv[d] = qsb[(size_t)d * 4096];
      qnv[d] = qnb[(size_t)d * 4096];
    }
    const float* ltp = lt + h * 216;
    const float* lbp = lb + h * 9;
    const float* rpp = rpb + h * 9;
    float wlv[9];
#pragma unroll
    for (int l = 0; l < 9; ++l) {
      float a0 = 0, a1 = 0, a2 = 0;
#pragma unroll
      for (int d = 0; d < 24; d += 3) {
        a0 += qnv[d] * ltp[d * 9 + l];
        a1 += qnv[d + 1] * ltp[(d + 1) * 9 + l];
        a2 += qnv[d + 2] * ltp[(d + 2) * 9 + l];
      }
      wlv[l] = a0 + a1 + a2 + lbp[l];
    }
    float S = 0.f;
#pragma unroll
    for (int d = 0; d < 24; ++d) { ctxA[d] = 0.f; ctxB[d] = 0.f; }
    const float* kbase = kmap + ((size_t)b * 384 + h * 24) * 4096;
#pragma unroll
    for (int l = 0; l < 9; ++l) {
      const int dh = l / 3 - 1, dw = l % 3 - 1;
      const int hp = hpix + dh;
      if (hp < 0 || hp >= 64) continue;
      const int wp2 = wpix + dw;
      const bool okw = (wp2 >= 0) && (wp2 < 64);
      const int nn = (hp << 6) + wp2;
      const float* kb = kbase + nn;
      const float* vb = kb + (size_t)192 * 4096;
      float d0 = 0, d1 = 0, d2 = 0, d3 = 0;
#pragma unroll
      for (int d = 0; d < 24; d += 4) {
        d0 += qsv[d] * kb[(size_t)d * 4096];
        d1 += qsv[d + 1] * kb[(size_t)(d + 1) * 4096];
        d2 += qsv[d + 2] * kb[(size_t)(d + 2) * 4096];
        d3 += qsv[d + 3] * kb[(size_t)(d + 3) * 4096];
      }
      float p = okw ? __expf((d0 + d1) + (d2 + d3) + rpp[l] - SHIFT) : 0.f;
      S += p;
      float wll = wlv[l];
#pragma unroll
      for (int d = 0; d < 24; ++d) {
        float vv = okw ? vb[(size_t)d * 4096] : 0.f;
        ctxA[d] += wll * vv;
        ctxB[d] += p * vv;
      }
    }
#pragma unroll
    for (int d = 0; d < 24; ++d) cls[wv][lane][d] = ctxB[d];
    cls[wv][lane][24] = S;
  }

  // ---- phase 2: pool part, wave w handles m-quarter for all 4 rows ----
  float qs4[4][24];
#pragma unroll
  for (int r = 0; r < 4; ++r) {
    const float* qsr = qs_g + ((size_t)(b * 8 + h) * 24) * 4096 + nblk + r * 64 + lane;
#pragma unroll
    for (int d = 0; d < 24; ++d) qs4[r][d] = qsr[(size_t)d * 4096];
  }
  float ctxP[4][24];
  float Sp[4];
#pragma unroll
  for (int r = 0; r < 4; ++r) {
    Sp[r] = 0.f;
#pragma unroll
    for (int d = 0; d < 24; ++d) ctxP[r][d] = 0.f;
  }
  __syncthreads();   // kl/vl staged + cls written

  const unsigned short* bbase = bt + (size_t)(h * 256) * 4096 + nblk + lane;
  for (int mq = 0; mq < 64; ++mq) {
    const int m = wv * 64 + mq;
    const float4* kr4 = (const float4*)&kl[m * 24];
    const float4* vr4 = (const float4*)&vl[m * 24];
    float4 k0 = kr4[0], k1 = kr4[1], k2 = kr4[2], k3 = kr4[3], k4 = kr4[4], k5 = kr4[5];
    const unsigned short* bm = bbase + (size_t)m * 4096;
    float pr[4];
#pragma unroll
    for (int r = 0; r < 4; ++r) {
      const float* q = qs4[r];
      float d0 = q[0] * k0.x + q[4] * k1.x + q[8] * k2.x + q[12] * k3.x + q[16] * k4.x + q[20] * k5.x;
      float d1 = q[1] * k0.y + q[5] * k1.y + q[9] * k2.y + q[13] * k3.y + q[17] * k4.y + q[21] * k5.y;
      float d2 = q[2] * k0.z + q[6] * k1.z + q[10] * k2.z + q[14] * k3.z + q[18] * k4.z + q[22] * k5.z;
      float d3 = q[3] * k0.w + q[7] * k1.w + q[11] * k2.w + q[15] * k3.w + q[19] * k4.w + q[23] * k5.w;
      float p = __expf((d0 + d1) + (d2 + d3) + b2f(bm[r * 64]) - SHIFT);
      Sp[r] += p;
      pr[r] = p;
    }
    float4 v0 = vr4[0], v1 = vr4[1], v2 = vr4[2], v3 = vr4[3], v4 = vr4[4], v5 = vr4[5];
#pragma unroll
    for (int r = 0; r < 4; ++r) {
      float p = pr[r];
      float* c = ctxP[r];
      c[0] += p * v0.x;  c[1] += p * v0.y;  c[2] += p * v0.z;  c[3] += p * v0.w;
      c[4] += p * v1.x;  c[5] += p * v1.y;  c[6] += p * v1.z;  c[7] += p * v1.w;
      c[8] += p * v2.x;  c[9] += p * v2.y;  c[10] += p * v2.z; c[11] += p * v2.w;
      c[12] += p * v3.x; c[13] += p * v3.y; c[14] += p * v3.z; c[15] += p * v3.w;
      c[16] += p * v4.x; c[17] += p * v4.y; c[18] += p * v4.z; c[19] += p * v4.w;
      c[20] += p * v5.x; c[21] += p * v5.y; c[22] += p * v5.z; c[23] += p * v5.w;
    }
  }

  // ---- phase 3: accumulate partials, then finalize own row ----
  __syncthreads();
  for (int w = 0; w < 4; ++w) {
    if (wv == w) {
#pragma unroll
      for (int r = 0; r < 4; ++r) {
#pragma unroll
        for (int d = 0; d < 24; ++d) cls[r][lane][d] += ctxP[r][d];
        cls[r][lane][24] += Sp[r];
      }
    }
    __syncthreads();
  }
  float inv = 1.f / cls[wv][lane][24];
  float* cb = ctx + ((size_t)(b * 8 + h) * 24) * 4096 + n;
#pragma unroll
  for (int d = 0; d < 24; ++d)
    cb[(size_t)d * 4096] = ctxA[d] + cls[wv][lane][d] * inv;
}

// ---------------- proj GEMM (96 oc/block) -> pout[b][o][n] + bias ----------------
__global__ __launch_bounds__(256) void k_projg(
    const float* __restrict__ ctx, const float* __restrict__ pjt, const float* __restrict__ pb,
    float* __restrict__ pout) {
  __shared__ __align__(16) float wl[32 * 96];
  __shared__ float xs[32 * 66];
  const int tid = threadIdx.x;
  const int lane = tid & 63;
  const int wv = __builtin_amdgcn_readfirstlane(tid >> 6);
  const int n0 = blockIdx.x * 64;
  const int b = blockIdx.y;
  const int obase = blockIdx.z * 96;
  const int oc0 = obase + wv * 24;
  const int n = n0 + lane;
  float acc[24];
#pragma unroll
  for (int j = 0; j < 24; ++j) acc[j] = 0.f;

  gemm_tiles<96>(wl, xs, tid, lane, wv, pjt, 192, obase, acc,
    [&](int k0, int f) {
      int kk = f >> 6, nl = f & 63;
      return ctx[((size_t)b * 192 + k0 + kk) * 4096 + n0 + nl];
    },
    [&](int f) { return (f >> 6) * 66 + (f & 63); });

#pragma unroll
  for (int d = 0; d < 24; ++d)
    pout[((size_t)b * 192 + oc0 + d) * 4096 + n] = acc[d] + pb[oc0 + d];
}

// ---------------- output LN over o (values in regs), out[b][o][n] ----------------
__global__ __launch_bounds__(256) void k_oln(
    const float* __restrict__ pout, const float* __restrict__ g,
    const float* __restrict__ be, float* __restrict__ out) {
  __shared__ float red[2][4][64];
  const int tid = threadIdx.x;
  const int lane = tid & 63;
  const int wv = __builtin_amdgcn_readfirstlane(tid >> 6);
  const int n0 = blockIdx.x * 64;
  const int b = blockIdx.y;
  const int o0 = wv * 48;
  float v[48];
  float s = 0.f, sq = 0.f;
#pragma unroll
  for (int j = 0; j < 48; ++j) {
    v[j] = pout[((size_t)b * 192 + o0 + j) * 4096 + n0 + lane];
    s += v[j];
    sq += v[j] * v[j];
  }
  red[0][wv][lane] = s;
  red[1][wv][lane] = sq;
  __syncthreads();
  float st = red[0][0][lane] + red[0][1][lane] + red[0][2][lane] + red[0][3][lane];
  float sqt = red[1][0][lane] + red[1][1][lane] + red[1][2][lane] + red[1][3][lane];
  float mean = st * (1.f / 192.f);
  float var = sqt * (1.f / 192.f) - mean * mean;
  float rstd = rsqrtf(var + 1e-5f);
#pragma unroll
  for (int j = 0; j < 48; ++j) {
    int o = o0 + j;
    out[((size_t)b * 192 + o) * 4096 + n0 + lane] = (v[j] - mean) * rstd * g[o] + be[o];
  }
}

// ---------------- host launcher ----------------
extern "C" void kernel_launch(void* const* d_in, const int* in_sizes, int n_in,
                              void* d_out, int out_size, void* d_ws, size_t ws_size,
                              hipStream_t stream) {
  float* w = (float*)d_ws;

  const float* x      = (const float*)d_in[0];
  const float* pe_w   = (const float*)d_in[1];
  const float* pe_b   = (const float*)d_in[2];
  const float* peln_g = (const float*)d_in[3];
  const float* peln_b = (const float*)d_in[4];
  const float* q_w    = (const float*)d_in[5];
  const float* q_b    = (const float*)d_in[6];
  const float* kv_w   = (const float*)d_in[7];
  const float* kv_b   = (const float*)d_in[8];
  const float* sr_w   = (const float*)d_in[9];
  const float* sr_b   = (const float*)d_in[10];
  const float* norm_g = (const float*)d_in[11];
  const float* norm_b = (const float*)d_in[12];
  const float* cpb1w  = (const float*)d_in[13];
  const float* cpb1b  = (const float*)d_in[14];
  const float* cpb2w  = (const float*)d_in[15];
  const float* cpb2b  = (const float*)d_in[16];
  const float* rpb    = (const float*)d_in[17];
  const float* lt     = (const float*)d_in[18];
  const float* lb     = (const float*)d_in[19];
  const float* qe     = (const float*)d_in[20];
  const float* temp   = (const float*)d_in[21];
  const float* proj_w = (const float*)d_in[22];
  const float* proj_b = (const float*)d_in[23];
  const float* oln_g  = (const float*)d_in[24];
  const float* oln_b  = (const float*)d_in[25];
  const int*   rel    = (const int*)d_in[26];
  const float* coords = (const float*)d_in[27];
  const float* ss     = (const float*)d_in[28];

  dim3 blk(256);
  k_wt_conv<<<dim3(1296), blk, 0, stream>>>(pe_w, w + OFF_WTC);
  k_wt_gen<<<dim3(144), blk, 0, stream>>>(q_w, w + OFF_QT, 192, 192);
  k_wt_gen<<<dim3(288), blk, 0, stream>>>(kv_w, w + OFF_KVT, 384, 192);
  k_wt_gen<<<dim3(144), blk, 0, stream>>>(sr_w, w + OFF_SRT, 192, 192);

  k_conv<<<dim3(32, 4, 4), blk, 0, stream>>>(x, w + OFF_WTC, pe_b, w + OFF_T);
  k_ln_rows<<<dim3(4096), blk, 0, stream>>>(w + OFF_T, peln_g, peln_b, 16384);
  k_q<<<dim3(64, 4, 2), blk, 0, stream>>>(w + OFF_T, w + OFF_QT, q_b, qe, temp, ss,
      w + OFF_QN, w + OFF_QS);
  k_kv<<<dim3(64, 4, 4), blk, 0, stream>>>(w + OFF_T, w + OFF_KVT, kv_b, w + OFF_KMAP);
  k_srpool<<<dim3(16, 16, 4), blk, 0, stream>>>(w + OFF_T, w + OFF_SRT, sr_b, w + OFF_POOL);
  k_ln_rows<<<dim3(256), blk, 0, stream>>>(w + OFF_POOL, norm_g, norm_b, 1024);
  k_kvp<<<dim3(16, 4), blk, 0, stream>>>(w + OFF_POOL, w + OFF_KVT, kv_b,
      w + OFF_KP, w + OFF_VP);
  int T = in_sizes[27] / 2;
  k_cpb<<<dim3((T + 255) / 256), blk, 0, stream>>>(coords, cpb1w, cpb1b, cpb2w, cpb2b,
      w + OFF_CPB, T);
  k_bias<<<dim3(16, 256), blk, 0, stream>>>(rel, w + OFF_CPB,
      (unsigned short*)(w + OFF_BIAS));
  k_attn<<<dim3(16, 8, 4), blk, 0, stream>>>(w + OFF_QS, w + OFF_QN, w + OFF_KMAP,
      w + OFF_KP, w + OFF_VP, (const unsigned short*)(w + OFF_BIAS), rpb, lt, lb,
      w + OFF_CTX);
  k_wt_gen<<<dim3(144), blk, 0, stream>>>(proj_w, w + OFF_PJT, 192, 192);
  k_projg<<<dim3(64, 4, 2), blk, 0, stream>>>(w + OFF_CTX, w + OFF_PJT, proj_b,
      w + OFF_QN);
  k_oln<<<dim3(64, 4), blk, 0, stream>>>(w + OFF_QN, oln_g, oln_b, (float*)d_out);
}